// Round 11
// baseline (107.752 us; speedup 1.0000x reference)
//
#include <hip/hip_runtime.h>
#include <hip/hip_bf16.h>
#include <hip/hip_fp16.h>

typedef unsigned int uint;
typedef unsigned short ushort;
typedef __attribute__((ext_vector_type(4))) float f32x4;
typedef __attribute__((ext_vector_type(8))) _Float16 f16x8;

// async global->LDS (used by tree_out staging only)
#define LDS16(gp, lp)                                                                    \
  __builtin_amdgcn_global_load_lds((const __attribute__((address_space(1))) uint*)(gp),  \
                                   (__attribute__((address_space(3))) uint*)(lp), 16, 0, 0)

// pack two f32 -> one u32 of two f16 (RTZ)
__device__ __forceinline__ uint pk_f16(float a, float b) {
  __fp16 __attribute__((ext_vector_type(2))) r = __builtin_amdgcn_cvt_pkrtz(a, b);
  union { decltype(r) v; uint u; } c;
  c.v = r;
  return c.u;
}

// ---------------------------------------------------------------------------
// Kernel 1: pack W into MFMA-fragment-ordered f16 via LDS transpose.
// ---------------------------------------------------------------------------
__global__ __launch_bounds__(256) void prep_b(const float* __restrict__ W,
                                              _Float16* __restrict__ Bpk) {
  __shared__ float t[64][65];
  const int tid = threadIdx.x;
  const int k0 = (blockIdx.x >> 3) * 64;
  const int c0 = (blockIdx.x & 7) * 64;
#pragma unroll
  for (int i = 0; i < 16; ++i) {
    int idx = i * 256 + tid;
    int kk = idx >> 6, cc = idx & 63;
    int c = c0 + cc;
    t[kk][cc] = (c < 511) ? W[(size_t)(k0 + kk) * 511 + c] : 0.f;
  }
  __syncthreads();
#pragma unroll
  for (int i = 0; i < 2; ++i) {
    int idx = i * 256 + tid;
    int fr = idx >> 6;
    int lane = idx & 63;
    int kt = fr >> 2, ct = fr & 3;
    int kt32 = (k0 >> 5) + kt, ct16 = (c0 >> 4) + ct;
    f16x8 v;
#pragma unroll
    for (int j = 0; j < 8; ++j)
      v[j] = (_Float16)t[kt * 32 + (lane >> 4) * 8 + j][ct * 16 + (lane & 15)];
    *(f16x8*)&Bpk[(size_t)((kt32 * 32 + ct16) * 64 + lane) * 8] = v;
  }
}

// ---------------------------------------------------------------------------
// Kernel 2 (ABLATION TEMPLATE): r10 barrier-free gemm, decomposed.
// MODE 0: prologue only.  MODE 1: + ds_read/MFMA loop (const B).
// MODE 2: + B L2-load loop only (loads kept live).  MODE 3: full (correct).
// ---------------------------------------------------------------------------
template <int MODE>
__global__ __launch_bounds__(1024) void gemm_abl(const float* __restrict__ X,
                                                 const _Float16* __restrict__ Bpk,
                                                 const float* __restrict__ bvec,
                                                 __half* __restrict__ P,
                                                 float* __restrict__ dummy) {
  __shared__ _Float16 ldsA[64 * 1024];  // 128 KB

  const int tid = threadIdx.x;
  const int lane = tid & 63;
  const int w = tid >> 6;
  const int l16 = lane & 15;
  const int g = lane >> 4;
  const int rbase = blockIdx.x * 64;

  // ---- prologue: stage full A panel, f32 -> f16, swizzled (identical all modes)
  {
    const int sr = tid & 63;
    const int skb = tid >> 6;
    const float* sSrc = X + (size_t)(rbase + sr) * 1024 + skb * 64;
    f32x4 xr[16];
#pragma unroll
    for (int i = 0; i < 16; ++i) xr[i] = *(const f32x4*)(sSrc + i * 4);
#pragma unroll
    for (int j = 0; j < 8; ++j) {
      union { uint u[4]; f16x8 v; } cc;
      cc.u[0] = pk_f16(xr[2 * j][0], xr[2 * j][1]);
      cc.u[1] = pk_f16(xr[2 * j][2], xr[2 * j][3]);
      cc.u[2] = pk_f16(xr[2 * j + 1][0], xr[2 * j + 1][1]);
      cc.u[3] = pk_f16(xr[2 * j + 1][2], xr[2 * j + 1][3]);
      *(f16x8*)&ldsA[sr * 1024 + (skb * 8 + (j ^ (sr & 7))) * 8] = cc.v;
    }
  }
  __syncthreads();

  if constexpr (MODE == 0) {
    dummy[blockIdx.x * 1024 + tid] = (float)ldsA[tid];  // keep LDS live
    return;
  } else {
    f32x4 acc[4][2];
#pragma unroll
    for (int i = 0; i < 4; ++i)
#pragma unroll
      for (int j = 0; j < 2; ++j) acc[i][j] = (f32x4)0.f;

    auto loadB = [&](f16x8* bR, int t) {
#pragma unroll
      for (int ni = 0; ni < 2; ++ni)
        bR[ni] = *(const f16x8*)&Bpk[(size_t)((t * 32 + 2 * w + ni) * 64 + lane) * 8];
    };

    auto computeK = [&](int t, const f16x8* bR) {
      f16x8 a[4];
#pragma unroll
      for (int mi = 0; mi < 4; ++mi) {
        int r = mi * 16 + l16;
        int c = t * 4 + g;
        int csw = (c & ~7) | ((c ^ (r & 7)) & 7);
        a[mi] = *(const f16x8*)&ldsA[r * 1024 + csw * 8];
      }
#pragma unroll
      for (int mi = 0; mi < 4; ++mi)
#pragma unroll
        for (int ni = 0; ni < 2; ++ni)
          acc[mi][ni] = __builtin_amdgcn_mfma_f32_16x16x32_f16(a[mi], bR[ni], acc[mi][ni], 0, 0, 0);
    };

    f16x8 bA[2], bB[2];
    if constexpr (MODE == 1) {
      // constant-ish B (from bvec, not DCE-foldable); no global B traffic
#pragma unroll
      for (int ni = 0; ni < 2; ++ni) {
#pragma unroll
        for (int j = 0; j < 8; ++j) bA[ni][j] = (_Float16)bvec[j];
        bB[ni] = bA[ni];
      }
    } else {
      loadB(bA, 0);
    }

#pragma unroll 1
    for (int t = 0; t < 32; t += 2) {
      if constexpr (MODE != 1) loadB(bB, t + 1);
      if constexpr (MODE != 2) {
        computeK(t, bA);
      } else {
        acc[0][0][0] += (float)bA[0][0] + (float)bA[1][0];  // forces load completion
      }
      if constexpr (MODE != 1) {
        if (t + 2 < 32) loadB(bA, t + 2);
      }
      if constexpr (MODE != 2) {
        computeK(t + 1, bB);
      } else {
        acc[0][0][0] += (float)bB[0][0] + (float)bB[1][0];
      }
    }

    if constexpr (MODE == 3) {
      // real epilogue: bias + sigmoid, store f16
#pragma unroll
      for (int ni = 0; ni < 2; ++ni) {
        int gc = (w << 5) + ni * 16 + l16;
        float bias = (gc < 511) ? bvec[gc] : 0.f;
#pragma unroll
        for (int mi = 0; mi < 4; ++mi) {
#pragma unroll
          for (int q = 0; q < 4; ++q) {
            int gr = rbase + mi * 16 + g * 4 + q;
            float z = acc[mi][ni][q] + bias;
            float pv = 1.f / (1.f + __expf(-z));
            P[(size_t)gr * 512 + gc] = __float2half(pv);
          }
        }
      }
    } else {
      // keep every acc chain live (one element keeps the whole MFMA tuple)
      float s = 0.f;
#pragma unroll
      for (int mi = 0; mi < 4; ++mi)
#pragma unroll
        for (int ni = 0; ni < 2; ++ni) s += acc[mi][ni][0];
      dummy[blockIdx.x * 1024 + tid] = s;
    }
  }
}

// ---------------------------------------------------------------------------
// Kernel 3: tree propagation + leaf matmul (f16 MFMA). Unchanged.
// ---------------------------------------------------------------------------
__global__ __launch_bounds__(256) void tree_out(const __half* __restrict__ P,
                                                const float* __restrict__ LL,
                                                float* __restrict__ out) {
  __shared__ __half plds[16 * 520];
  __shared__ f32x4 red[4][64];
  const int tid = threadIdx.x;
  const int lane = tid & 63;
  const int wid = tid >> 6;
  const int r = lane & 15;
  const int g = lane >> 4;
  const int rbase = blockIdx.x * 16;

#pragma unroll
  for (int i = 0; i < 4; ++i) {
    int row = wid * 4 + i;
    LDS16(P + (size_t)(rbase + row) * 512 + lane * 8, plds + row * 520 + lane * 8);
  }

  f16x8 bfr[4];
  const int col = r;
#pragma unroll
  for (int tt = 0; tt < 4; ++tt) {
    int t = wid * 4 + tt;
#pragma unroll
    for (int p = 0; p < 8; ++p) {
      int k0 = t * 32 + g * 8 + p;
      bfr[tt][p] = (col < 10) ? (_Float16)LL[k0 * 10 + col] : (_Float16)0.f;
    }
  }

  __syncthreads();

  const __half* prow = &plds[r * 520];
  f32x4 acc = (f32x4)0.f;
#pragma unroll
  for (int tt = 0; tt < 4; ++tt) {
    const int t = wid * 4 + tt;
    const int L0 = g * 8 + 32 * t;
    float pref = 1.f;
#pragma unroll
    for (int k = 0; k < 6; ++k) {
      int node = L0 >> (9 - k);
      int bit = (L0 >> (8 - k)) & 1;
      float pv = __half2float(prow[(1 << k) - 1 + node]);
      pref *= bit ? pv : (1.f - pv);
    }
    float p6 = __half2float(prow[63 + (L0 >> 3)]);
    float p7a = __half2float(prow[127 + (L0 >> 2)]);
    float p7b = __half2float(prow[128 + (L0 >> 2)]);
    float p80 = __half2float(prow[255 + (L0 >> 1)]);
    float p81 = __half2float(prow[256 + (L0 >> 1)]);
    float p82 = __half2float(prow[257 + (L0 >> 1)]);
    float p83 = __half2float(prow[258 + (L0 >> 1)]);
    float u1 = pref * p6, u0 = pref - u1;
    float v01 = u0 * p7a, v00 = u0 - v01;
    float v11 = u1 * p7b, v10 = u1 - v11;
    float pr1 = v00 * p80, pr0 = v00 - pr1;
    float pr3 = v01 * p81, pr2 = v01 - pr3;
    float pr5 = v10 * p82, pr4 = v10 - pr5;
    float pr7 = v11 * p83, pr6 = v11 - pr7;
    f16x8 af;
    af[0] = (_Float16)pr0; af[1] = (_Float16)pr1;
    af[2] = (_Float16)pr2; af[3] = (_Float16)pr3;
    af[4] = (_Float16)pr4; af[5] = (_Float16)pr5;
    af[6] = (_Float16)pr6; af[7] = (_Float16)pr7;
    acc = __builtin_amdgcn_mfma_f32_16x16x32_f16(af, bfr[tt], acc, 0, 0, 0);
  }

  red[wid][lane] = acc;
  __syncthreads();
  if (wid == 0 && col < 10) {
    f32x4 a0 = red[0][lane], a1 = red[1][lane], a2 = red[2][lane], a3 = red[3][lane];
#pragma unroll
    for (int q = 0; q < 4; ++q)
      out[(size_t)(rbase + g * 4 + q) * 10 + col] = a0[q] + a1[q] + a2[q] + a3[q];
  }
}

// ---------------------------------------------------------------------------
extern "C" void kernel_launch(void* const* d_in, const int* in_sizes, int n_in,
                              void* d_out, int out_size, void* d_ws, size_t ws_size,
                              hipStream_t stream) {
  const float* X = (const float*)d_in[0];
  const float* W = (const float*)d_in[1];
  const float* bv = (const float*)d_in[2];
  const float* LL = (const float*)d_in[3];
  float* out = (float*)d_out;

  __half* P = (__half*)d_ws;                                           // 16 MB
  _Float16* Bpk = (_Float16*)((char*)d_ws + (size_t)16384 * 512 * 2);  // 1 MB
  float* dummy = (float*)((char*)d_ws + (size_t)18 * 1024 * 1024);     // 1 MB scratch

  prep_b<<<128, 256, 0, stream>>>(W, Bpk);
  gemm_abl<0><<<256, 1024, 0, stream>>>(X, Bpk, bv, P, dummy);  // prologue only
  gemm_abl<2><<<256, 1024, 0, stream>>>(X, Bpk, bv, P, dummy);  // + B-loads only
  gemm_abl<1><<<256, 1024, 0, stream>>>(X, Bpk, bv, P, dummy);  // + LDS/MFMA only
  gemm_abl<3><<<256, 1024, 0, stream>>>(X, Bpk, bv, P, dummy);  // full (writes P)
  tree_out<<<1024, 256, 0, stream>>>(P, LL, out);
}

// Round 12
// 70.954 us; speedup vs baseline: 1.5186x; 1.5186x over previous
//
#include <hip/hip_runtime.h>
#include <hip/hip_bf16.h>
#include <hip/hip_fp16.h>

typedef unsigned int uint;
typedef unsigned short ushort;
typedef __attribute__((ext_vector_type(4))) float f32x4;
typedef __attribute__((ext_vector_type(8))) _Float16 f16x8;

// async global->LDS (used by tree_out staging only)
#define LDS16(gp, lp)                                                                    \
  __builtin_amdgcn_global_load_lds((const __attribute__((address_space(1))) uint*)(gp),  \
                                   (__attribute__((address_space(3))) uint*)(lp), 16, 0, 0)

// pack two f32 -> one u32 of two f16 (RTZ)
__device__ __forceinline__ uint pk_f16(float a, float b) {
  __fp16 __attribute__((ext_vector_type(2))) r = __builtin_amdgcn_cvt_pkrtz(a, b);
  union { decltype(r) v; uint u; } c;
  c.v = r;
  return c.u;
}

// ---------------------------------------------------------------------------
// Kernel 1: pack W into MFMA-fragment-ordered f16 via LDS transpose.
// Bpk[((t32*32 + ct16)*64 + lane)*8 + j] = W[t32*32 + (lane>>4)*8 + j][ct16*16 + (lane&15)]
// ---------------------------------------------------------------------------
__global__ __launch_bounds__(256) void prep_b(const float* __restrict__ W,
                                              _Float16* __restrict__ Bpk) {
  __shared__ float t[64][65];
  const int tid = threadIdx.x;
  const int k0 = (blockIdx.x >> 3) * 64;
  const int c0 = (blockIdx.x & 7) * 64;
#pragma unroll
  for (int i = 0; i < 16; ++i) {
    int idx = i * 256 + tid;
    int kk = idx >> 6, cc = idx & 63;
    int c = c0 + cc;
    t[kk][cc] = (c < 511) ? W[(size_t)(k0 + kk) * 511 + c] : 0.f;
  }
  __syncthreads();
#pragma unroll
  for (int i = 0; i < 2; ++i) {
    int idx = i * 256 + tid;
    int fr = idx >> 6;
    int lane = idx & 63;
    int kt = fr >> 2, ct = fr & 3;
    int kt32 = (k0 >> 5) + kt, ct16 = (c0 >> 4) + ct;
    f16x8 v;
#pragma unroll
    for (int j = 0; j < 8; ++j)
      v[j] = (_Float16)t[kt * 32 + (lane >> 4) * 8 + j][ct * 16 + (lane & 15)];
    *(f16x8*)&Bpk[(size_t)((kt32 * 32 + ct16) * 64 + lane) * 8] = v;
  }
}

// ---------------------------------------------------------------------------
// Kernel 2: P = sigmoid(X @ W + b), f16 [16384][512] (col 511 junk).
// r10 barrier-free structure; ONLY the wave split changes: 16 waves as
// 4M x 4N (wave tile 16 x 128). The 4 waves of a column-group read the SAME
// 8KB of packed B per k-step -> B becomes L1-resident (3 of 4 reads hit L1),
// cutting per-CU L1-miss traffic ~2.5x. Per iter/wave: 8 B-loads (mostly L1),
// 1 ds_read_b128, 8 MFMA. B double-buffered in regs, pure reg deps.
// ---------------------------------------------------------------------------
__global__ __launch_bounds__(1024, 1) void gemm_sig(const float* __restrict__ X,
                                                    const _Float16* __restrict__ Bpk,
                                                    const float* __restrict__ bvec,
                                                    __half* __restrict__ P) {
  __shared__ _Float16 ldsA[64 * 1024];  // 128 KB: [row][k], 16B chunks XOR-swizzled

  const int tid = threadIdx.x;  // 0..1023
  const int lane = tid & 63;
  const int w = tid >> 6;       // 0..15
  const int wm = w >> 2;        // 0..3: row group (16 rows)
  const int wn = w & 3;         // 0..3: col group (128 cols)
  const int l16 = lane & 15;
  const int g = lane >> 4;
  const int rbase = blockIdx.x * 64;

  // ---- prologue: stage full A panel, f32 -> f16, swizzled (identical to r10)
  {
    const int sr = tid & 63;
    const int skb = tid >> 6;
    const float* sSrc = X + (size_t)(rbase + sr) * 1024 + skb * 64;
    f32x4 xr[16];
#pragma unroll
    for (int i = 0; i < 16; ++i) xr[i] = *(const f32x4*)(sSrc + i * 4);
#pragma unroll
    for (int j = 0; j < 8; ++j) {
      union { uint u[4]; f16x8 v; } cc;
      cc.u[0] = pk_f16(xr[2 * j][0], xr[2 * j][1]);
      cc.u[1] = pk_f16(xr[2 * j][2], xr[2 * j][3]);
      cc.u[2] = pk_f16(xr[2 * j + 1][0], xr[2 * j + 1][1]);
      cc.u[3] = pk_f16(xr[2 * j + 1][2], xr[2 * j + 1][3]);
      *(f16x8*)&ldsA[sr * 1024 + (skb * 8 + (j ^ (sr & 7))) * 8] = cc.v;
    }
  }
  __syncthreads();  // the ONLY barrier

  f32x4 acc[8];
#pragma unroll
  for (int i = 0; i < 8; ++i) acc[i] = (f32x4)0.f;

  auto loadB = [&](f16x8* bR, int t) {  // 8 x 1KB wave-loads; 4 waves share them (L1 hits)
#pragma unroll
    for (int ni = 0; ni < 8; ++ni)
      bR[ni] = *(const f16x8*)&Bpk[(size_t)((t * 32 + wn * 8 + ni) * 64 + lane) * 8];
  };

  auto computeK = [&](int t, const f16x8* bR) {
    const int r = wm * 16 + l16;
    const int c = t * 4 + g;
    const int csw = (c & ~7) | ((c ^ (r & 7)) & 7);
    const f16x8 a = *(const f16x8*)&ldsA[r * 1024 + csw * 8];
#pragma unroll
    for (int ni = 0; ni < 8; ++ni)
      acc[ni] = __builtin_amdgcn_mfma_f32_16x16x32_f16(a, bR[ni], acc[ni], 0, 0, 0);
  };

  f16x8 bA[8], bB[8];
  loadB(bA, 0);
#pragma unroll 1
  for (int t = 0; t < 32; t += 2) {
    loadB(bB, t + 1);            // prefetch next (reg dep, compiler-counted wait)
    computeK(t, bA);
    if (t + 2 < 32) loadB(bA, t + 2);
    computeK(t + 1, bB);
  }

  // epilogue: bias + sigmoid, store f16
#pragma unroll
  for (int ni = 0; ni < 8; ++ni) {
    int gc = wn * 128 + ni * 16 + l16;
    float bias = (gc < 511) ? bvec[gc] : 0.f;
#pragma unroll
    for (int q = 0; q < 4; ++q) {
      int gr = rbase + wm * 16 + g * 4 + q;
      float z = acc[ni][q] + bias;
      float pv = 1.f / (1.f + __expf(-z));
      P[(size_t)gr * 512 + gc] = __float2half(pv);
    }
  }
}

// ---------------------------------------------------------------------------
// Kernel 3: tree propagation + leaf matmul (f16 MFMA). Unchanged.
// ---------------------------------------------------------------------------
__global__ __launch_bounds__(256) void tree_out(const __half* __restrict__ P,
                                                const float* __restrict__ LL,
                                                float* __restrict__ out) {
  __shared__ __half plds[16 * 520];
  __shared__ f32x4 red[4][64];
  const int tid = threadIdx.x;
  const int lane = tid & 63;
  const int wid = tid >> 6;
  const int r = lane & 15;
  const int g = lane >> 4;
  const int rbase = blockIdx.x * 16;

#pragma unroll
  for (int i = 0; i < 4; ++i) {
    int row = wid * 4 + i;
    LDS16(P + (size_t)(rbase + row) * 512 + lane * 8, plds + row * 520 + lane * 8);
  }

  f16x8 bfr[4];
  const int col = r;
#pragma unroll
  for (int tt = 0; tt < 4; ++tt) {
    int t = wid * 4 + tt;
#pragma unroll
    for (int p = 0; p < 8; ++p) {
      int k0 = t * 32 + g * 8 + p;
      bfr[tt][p] = (col < 10) ? (_Float16)LL[k0 * 10 + col] : (_Float16)0.f;
    }
  }

  __syncthreads();

  const __half* prow = &plds[r * 520];
  f32x4 acc = (f32x4)0.f;
#pragma unroll
  for (int tt = 0; tt < 4; ++tt) {
    const int t = wid * 4 + tt;
    const int L0 = g * 8 + 32 * t;
    float pref = 1.f;
#pragma unroll
    for (int k = 0; k < 6; ++k) {
      int node = L0 >> (9 - k);
      int bit = (L0 >> (8 - k)) & 1;
      float pv = __half2float(prow[(1 << k) - 1 + node]);
      pref *= bit ? pv : (1.f - pv);
    }
    float p6 = __half2float(prow[63 + (L0 >> 3)]);
    float p7a = __half2float(prow[127 + (L0 >> 2)]);
    float p7b = __half2float(prow[128 + (L0 >> 2)]);
    float p80 = __half2float(prow[255 + (L0 >> 1)]);
    float p81 = __half2float(prow[256 + (L0 >> 1)]);
    float p82 = __half2float(prow[257 + (L0 >> 1)]);
    float p83 = __half2float(prow[258 + (L0 >> 1)]);
    float u1 = pref * p6, u0 = pref - u1;
    float v01 = u0 * p7a, v00 = u0 - v01;
    float v11 = u1 * p7b, v10 = u1 - v11;
    float pr1 = v00 * p80, pr0 = v00 - pr1;
    float pr3 = v01 * p81, pr2 = v01 - pr3;
    float pr5 = v10 * p82, pr4 = v10 - pr5;
    float pr7 = v11 * p83, pr6 = v11 - pr7;
    f16x8 af;
    af[0] = (_Float16)pr0; af[1] = (_Float16)pr1;
    af[2] = (_Float16)pr2; af[3] = (_Float16)pr3;
    af[4] = (_Float16)pr4; af[5] = (_Float16)pr5;
    af[6] = (_Float16)pr6; af[7] = (_Float16)pr7;
    acc = __builtin_amdgcn_mfma_f32_16x16x32_f16(af, bfr[tt], acc, 0, 0, 0);
  }

  red[wid][lane] = acc;
  __syncthreads();
  if (wid == 0 && col < 10) {
    f32x4 a0 = red[0][lane], a1 = red[1][lane], a2 = red[2][lane], a3 = red[3][lane];
#pragma unroll
    for (int q = 0; q < 4; ++q)
      out[(size_t)(rbase + g * 4 + q) * 10 + col] = a0[q] + a1[q] + a2[q] + a3[q];
  }
}

// ---------------------------------------------------------------------------
extern "C" void kernel_launch(void* const* d_in, const int* in_sizes, int n_in,
                              void* d_out, int out_size, void* d_ws, size_t ws_size,
                              hipStream_t stream) {
  const float* X = (const float*)d_in[0];
  const float* W = (const float*)d_in[1];
  const float* bv = (const float*)d_in[2];
  const float* LL = (const float*)d_in[3];
  float* out = (float*)d_out;

  __half* P = (__half*)d_ws;                                          // 16 MB
  _Float16* Bpk = (_Float16*)((char*)d_ws + (size_t)16384 * 512 * 2); // 1 MB

  prep_b<<<128, 256, 0, stream>>>(W, Bpk);
  gemm_sig<<<256, 1024, 0, stream>>>(X, Bpk, bv, P);
  tree_out<<<1024, 256, 0, stream>>>(P, LL, out);
}

// Round 13
// 47.028 us; speedup vs baseline: 2.2912x; 1.5088x over previous
//
#include <hip/hip_runtime.h>
#include <hip/hip_bf16.h>
#include <hip/hip_fp16.h>

typedef unsigned int uint;
typedef unsigned short ushort;
typedef __attribute__((ext_vector_type(4))) float f32x4;
typedef __attribute__((ext_vector_type(8))) _Float16 f16x8;

// async global->LDS, 16B per lane; LDS dest is wave-uniform-base + lane*16 (linear)
#define LDS16(gp, lp)                                                                    \
  __builtin_amdgcn_global_load_lds((const __attribute__((address_space(1))) uint*)(gp),  \
                                   (__attribute__((address_space(3))) uint*)(lp), 16, 0, 0)

// pack two f32 -> one u32 of two f16 (RTZ)
__device__ __forceinline__ uint pk_f16(float a, float b) {
  __fp16 __attribute__((ext_vector_type(2))) r = __builtin_amdgcn_cvt_pkrtz(a, b);
  union { decltype(r) v; uint u; } c;
  c.v = r;
  return c.u;
}

// ---------------------------------------------------------------------------
// Kernel 1: W (1024x511 f32, row-major) -> transposed f16 [512][1024],
// col 511 zero-padded. LDS 64x65 tile transpose keeps both sides coalesced.
// ---------------------------------------------------------------------------
__global__ __launch_bounds__(256) void prep_w(const float* __restrict__ W,
                                              _Float16* __restrict__ WT) {
  __shared__ float t[64][65];
  const int tid = threadIdx.x;
  const int k0 = (blockIdx.x >> 3) * 64;
  const int n0 = (blockIdx.x & 7) * 64;
#pragma unroll
  for (int i = 0; i < 16; ++i) {
    int idx = i * 256 + tid;
    int kk = idx >> 6, nn = idx & 63;
    int n = n0 + nn;
    t[kk][nn] = (n < 511) ? W[(size_t)(k0 + kk) * 511 + n] : 0.f;
  }
  __syncthreads();
#pragma unroll
  for (int i = 0; i < 16; ++i) {
    int idx = i * 256 + tid;
    int nn = idx >> 6, kk = idx & 63;
    WT[(size_t)(n0 + nn) * 1024 + k0 + kk] = (_Float16)t[kk][nn];
  }
}

// ---------------------------------------------------------------------------
// Kernel 2 (FUSED): out[64x10] per block, no P round-trip.
// Stage 1 = r8's best gemm verbatim: 64 rows x FULL 512 cols, 1024 threads
// (16 waves 2Mx8N), BK=64, counted vmcnt(4), A reg-staged, B via
// global_load_lds. Stage 2 = sigmoid -> P in LDS (reuse B buffers, stride
// 520) -> tree propagation + leaf MFMA in-block -> 64x10 f32 out.
// ---------------------------------------------------------------------------
__global__ __launch_bounds__(1024, 1) void gemm_tree(const float* __restrict__ X,
                                                     const _Float16* __restrict__ WT,
                                                     const float* __restrict__ bvec,
                                                     const float* __restrict__ LL,
                                                     float* __restrict__ out) {
  __shared__ _Float16 ldsB[2][512 * 64];   // 128 KB; reused as plds+red after K-loop
  __shared__ _Float16 ldsA[2][64 * 64];    // 16 KB

  const int tid = threadIdx.x;            // 0..1023
  const int lane = tid & 63;
  const int w = tid >> 6;                 // 0..15
  const int wr = w >> 3, wc = w & 7;      // 2(M) x 8(N)
  const int l16 = lane & 15;
  const int g = lane >> 4;
  const int rbase = blockIdx.x * 64;

  // A staging (threads 0..511): row = tid>>3, 8 consecutive f32 per thread
  const bool doA = (tid < 512);
  const int arow = tid >> 3;
  const int aseg = tid & 7;
  const float* aSrc = X + (size_t)(rbase + arow) * 1024 + aseg * 8;
  const int awOff = arow * 64 + (aseg ^ (arow & 7)) * 8;  // swizzled 16B slot

  f32x4 acc[2][4];
#pragma unroll
  for (int i = 0; i < 2; ++i)
#pragma unroll
    for (int j = 0; j < 4; ++j) acc[i][j] = (f32x4)0.f;

  f32x4 aReg[2];

  auto issueA = [&](int kt) {
    if (doA) {
      const float* s = aSrc + kt * 64;
      aReg[0] = *(const f32x4*)(s);
      aReg[1] = *(const f32x4*)(s + 4);
    }
  };

  auto writeA = [&](int buf) {
    if (doA) {
      union { uint u[4]; f16x8 v; } c;
      c.u[0] = pk_f16(aReg[0][0], aReg[0][1]);
      c.u[1] = pk_f16(aReg[0][2], aReg[0][3]);
      c.u[2] = pk_f16(aReg[1][0], aReg[1][1]);
      c.u[3] = pk_f16(aReg[1][2], aReg[1][3]);
      *(f16x8*)&ldsA[buf][awOff] = c.v;
    }
  };

  auto issueB = [&](int buf, int kt) {
#pragma unroll
    for (int i = 0; i < 4; ++i) {
      int l = tid + 1024 * i;
      int c = l >> 3, gp = l & 7;
      int gs = gp ^ (c & 7);
      LDS16(WT + (size_t)c * 1024 + kt * 64 + gs * 8, &ldsB[buf][l * 8]);
    }
  };

  auto compute = [&](int buf) {
#pragma unroll
    for (int kk = 0; kk < 2; ++kk) {
      f16x8 b[4], a[2];
#pragma unroll
      for (int ni = 0; ni < 4; ++ni) {
        int c = wc * 64 + ni * 16 + l16;
        b[ni] = *(const f16x8*)&ldsB[buf][c * 64 + (((kk * 4 + g) ^ (c & 7)) * 8)];
      }
#pragma unroll
      for (int mi = 0; mi < 2; ++mi) {
        int r = wr * 32 + mi * 16 + l16;
        a[mi] = *(const f16x8*)&ldsA[buf][r * 64 + (((kk * 4 + g) ^ (r & 7)) * 8)];
      }
#pragma unroll
      for (int mi = 0; mi < 2; ++mi)
#pragma unroll
        for (int ni = 0; ni < 4; ++ni)
          acc[mi][ni] = __builtin_amdgcn_mfma_f32_16x16x32_f16(a[mi], b[ni], acc[mi][ni], 0, 0, 0);
    }
  };

  // prologue: B(0)[4], A(0)[2], B(1)[4] in flight
  issueB(0, 0);
  issueA(0);
  issueB(1, 1);

#pragma unroll
  for (int t = 0; t < 16; ++t) {
    const int buf = t & 1;
    if (t < 15) {
      asm volatile("s_waitcnt vmcnt(4)" ::: "memory");
    } else {
      asm volatile("s_waitcnt vmcnt(0)" ::: "memory");
    }
    __builtin_amdgcn_sched_barrier(0);
    writeA(buf);
    asm volatile("s_waitcnt lgkmcnt(0)" ::: "memory");
    __builtin_amdgcn_sched_barrier(0);
    __builtin_amdgcn_s_barrier();
    __builtin_amdgcn_sched_barrier(0);
    if (t + 1 < 16) issueA(t + 1);
    __builtin_amdgcn_sched_barrier(0);
    __builtin_amdgcn_s_setprio(1);
    compute(buf);
    __builtin_amdgcn_s_setprio(0);
    __builtin_amdgcn_sched_barrier(0);
    __builtin_amdgcn_s_barrier();                  // all waves done with buf
    if (t + 2 < 16) issueB(buf, t + 2);
  }
  // after final barrier: no wave touches ldsB as B again -> safe to reuse

  // ---- stage 2a: sigmoid -> P in LDS (padded stride 520) ----
  __half* plds = (__half*)&ldsB[0][0];                       // 64 x 520 = 66.5 KB
  f32x4* red = (f32x4*)((char*)&ldsB[0][0] + 68 * 1024);     // [4 rg][3 tw-1][64] = 48 KB
#pragma unroll
  for (int mi = 0; mi < 2; ++mi) {
#pragma unroll
    for (int ni = 0; ni < 4; ++ni) {
      int gc = wc * 64 + ni * 16 + l16;
      float bias = (gc < 511) ? bvec[gc] : 0.f;
#pragma unroll
      for (int q = 0; q < 4; ++q) {
        int lr = wr * 32 + mi * 16 + g * 4 + q;   // local row 0..63
        float z = acc[mi][ni][q] + bias;
        float pv = 1.f / (1.f + __expf(-z));
        plds[lr * 520 + gc] = __float2half(pv);
      }
    }
  }
  __syncthreads();

  // ---- stage 2b: tree propagation + leaf MFMA ----
  // wave w: rg = w>>2 (16-row group), tw = w&3 (4 t-chunks t = tw*4+tt)
  const int rg = w >> 2, tw = w & 3;
  const int r = lane & 15;   // row within group; also LL col
  const int col = r;

  f16x8 bfr[4];
#pragma unroll
  for (int tt = 0; tt < 4; ++tt) {
    int t = tw * 4 + tt;
#pragma unroll
    for (int p = 0; p < 8; ++p) {
      int k0 = t * 32 + g * 8 + p;
      bfr[tt][p] = (col < 10) ? (_Float16)LL[k0 * 10 + col] : (_Float16)0.f;
    }
  }

  const __half* prow = &plds[(rg * 16 + r) * 520];
  f32x4 tacc = (f32x4)0.f;
#pragma unroll
  for (int tt = 0; tt < 4; ++tt) {
    const int t = tw * 4 + tt;
    const int L0 = g * 8 + 32 * t;
    float pref = 1.f;
#pragma unroll
    for (int k = 0; k < 6; ++k) {
      int node = L0 >> (9 - k);
      int bit = (L0 >> (8 - k)) & 1;
      float pv = __half2float(prow[(1 << k) - 1 + node]);
      pref *= bit ? pv : (1.f - pv);
    }
    float p6 = __half2float(prow[63 + (L0 >> 3)]);
    float p7a = __half2float(prow[127 + (L0 >> 2)]);
    float p7b = __half2float(prow[128 + (L0 >> 2)]);
    float p80 = __half2float(prow[255 + (L0 >> 1)]);
    float p81 = __half2float(prow[256 + (L0 >> 1)]);
    float p82 = __half2float(prow[257 + (L0 >> 1)]);
    float p83 = __half2float(prow[258 + (L0 >> 1)]);
    float u1 = pref * p6, u0 = pref - u1;
    float v01 = u0 * p7a, v00 = u0 - v01;
    float v11 = u1 * p7b, v10 = u1 - v11;
    float pr1 = v00 * p80, pr0 = v00 - pr1;
    float pr3 = v01 * p81, pr2 = v01 - pr3;
    float pr5 = v10 * p82, pr4 = v10 - pr5;
    float pr7 = v11 * p83, pr6 = v11 - pr7;
    f16x8 af;
    af[0] = (_Float16)pr0; af[1] = (_Float16)pr1;
    af[2] = (_Float16)pr2; af[3] = (_Float16)pr3;
    af[4] = (_Float16)pr4; af[5] = (_Float16)pr5;
    af[6] = (_Float16)pr6; af[7] = (_Float16)pr7;
    tacc = __builtin_amdgcn_mfma_f32_16x16x32_f16(af, bfr[tt], tacc, 0, 0, 0);
  }

  if (tw > 0) red[(rg * 3 + (tw - 1)) * 64 + lane] = tacc;
  __syncthreads();

  if (tw == 0 && col < 10) {
    f32x4 a1 = red[(rg * 3 + 0) * 64 + lane];
    f32x4 a2 = red[(rg * 3 + 1) * 64 + lane];
    f32x4 a3 = red[(rg * 3 + 2) * 64 + lane];
#pragma unroll
    for (int q = 0; q < 4; ++q)
      out[(size_t)(rbase + rg * 16 + g * 4 + q) * 10 + col] =
          tacc[q] + a1[q] + a2[q] + a3[q];
  }
}

// ---------------------------------------------------------------------------
extern "C" void kernel_launch(void* const* d_in, const int* in_sizes, int n_in,
                              void* d_out, int out_size, void* d_ws, size_t ws_size,
                              hipStream_t stream) {
  const float* X = (const float*)d_in[0];
  const float* W = (const float*)d_in[1];
  const float* bv = (const float*)d_in[2];
  const float* LL = (const float*)d_in[3];
  float* out = (float*)d_out;

  _Float16* WT = (_Float16*)d_ws;  // 1 MB

  prep_w<<<128, 256, 0, stream>>>(W, WT);
  gemm_tree<<<256, 1024, 0, stream>>>(X, WT, bv, LL, out);
}